// Round 1
// baseline (2547.087 us; speedup 1.0000x reference)
//
#include <hip/hip_runtime.h>
#include <math.h>

typedef __bf16 bf16;
typedef __bf16 bf16x8 __attribute__((ext_vector_type(8)));
typedef float f32x4 __attribute__((ext_vector_type(4)));

#define ZDIM 17728
#define HIDN 4096
#define BSZ 128

__device__ __forceinline__ void gl_lds16(const bf16* g, bf16* l) {
  __builtin_amdgcn_global_load_lds(
      (const __attribute__((address_space(1))) unsigned int*)g,
      (__attribute__((address_space(3))) unsigned int*)l, 16, 0, 0);
}

// ---------- cast + transpose: src (K x N) f32 -> dst (N x K) bf16 ----------
__global__ void k_cast_transpose(const float* __restrict__ src, bf16* __restrict__ dst,
                                 int K, int N) {
  __shared__ float t[32][33];
  int tx = threadIdx.x, ty = threadIdx.y;  // 32 x 8
  int k0 = blockIdx.y * 32, n0 = blockIdx.x * 32;
#pragma unroll
  for (int i = 0; i < 32; i += 8)
    t[ty + i][tx] = src[(size_t)(k0 + ty + i) * N + (n0 + tx)];
  __syncthreads();
#pragma unroll
  for (int i = 0; i < 32; i += 8)
    dst[(size_t)(n0 + ty + i) * K + (k0 + tx)] = (bf16)t[tx][ty + i];
}

// ---------- build z0 (fp32 into d_out, bf16 copy) ----------
__global__ void k_build_z0(const float* __restrict__ input_freq, const int* __restrict__ seq,
                           const int* __restrict__ uid, const float* __restrict__ fuse,
                           const int* __restrict__ n_poi_p,
                           float* __restrict__ z, bf16* __restrict__ zb) {
  int n = blockIdx.x * 256 + threadIdx.x;
  int b = blockIdx.y;
  if (n >= ZDIM) return;
  float v;
  if (n < 9408) {
    v = input_freq[b * 3136 + (n % 3136)];
  } else if (n < 17600) {
    int m = n - 9408;
    int d = m >> 6, l = m & 63;
    v = fuse[(size_t)seq[b * 64 + l] * 128 + d];
  } else {
    int d = n - 17600;
    v = fuse[(size_t)(n_poi_p[0] + uid[b]) * 128 + d];
  }
  size_t idx = (size_t)b * ZDIM + n;
  z[idx] = v;
  zb[idx] = (bf16)v;
}

// ---------- time grid + sin/cos embedding: E[12][128][6] ----------
__global__ void k_build_emb(const float* __restrict__ cur, const float* __restrict__ tar,
                            float* __restrict__ E) {
  int b = threadIdx.x;  // 128 threads
  const float P[3] = {24.0f, 7.0f, 365.0f};
  const float TWO_PI = 6.283185307179586f;
  float t[3];
  for (int c = 0; c < 3; ++c) t[c] = cur[b * 3 + c];
  int r = 0;
  for (int j = 0; j < 3; ++j) {
    float s = cur[b * 3 + j], e = tar[b * 3 + j];
    bool wrap = s > e;
    float ea = wrap ? (e + P[j]) : e;
    for (int k = 0; k < 4; ++k) {
      float frac = (float)k / 3.0f;  // matches jnp.linspace(0,1,4)
      float v = s + (ea - s) * frac;
      if (wrap) v = v - floorf(v / P[j]) * P[j];  // jnp.mod semantics (positive args)
      t[j] = v;
      for (int c = 0; c < 3; ++c) {
        float ph = TWO_PI * t[c] / P[c];
        E[(r * BSZ + b) * 6 + c] = sinf(ph);
        E[(r * BSZ + b) * 6 + 3 + c] = cosf(ph);
      }
      ++r;
    }
  }
}

// ---------- GEMM1 partial: P[kc] = A(128xK-chunk) * W1t^T, K split 8 ways ----------
// A: Zb 128 x 17728 row-major (bf16). Bt: W1t 4096 x 17728 row-major (bf16, = W1^T).
__global__ __launch_bounds__(256, 2) void k_gemm1(const bf16* __restrict__ A,
                                                  const bf16* __restrict__ Bt,
                                                  float* __restrict__ P) {
  __shared__ __align__(16) bf16 As[128 * 32];
  __shared__ __align__(16) bf16 Bs[128 * 32];
  const int tid = threadIdx.x;
  const int w = tid >> 6, lane = tid & 63;
  const int q = lane >> 4, r = lane & 15;
  const int nt = blockIdx.x, kc = blockIdx.y;
  const int nsteps = (kc < 2) ? 70 : 69;           // 554 = 8*69 + 2 k-steps of 32
  const int kstart = kc * 69 + ((kc < 2) ? kc : 2);

  // staging: per wave 2 instrs each for A and B; 16 rows x 64B per instr
  const int srow = lane >> 2, sslot = lane & 3;
  const int sg = sslot ^ ((srow >> 2) & 3);        // XOR swizzle (store side)
  const int rA0 = (2 * w) * 16 + srow;
  const int rA1 = (2 * w + 1) * 16 + srow;
  long k0 = (long)kstart * 32;
  const bf16* pA0 = A + (size_t)rA0 * ZDIM + k0 + sg * 8;
  const bf16* pA1 = A + (size_t)rA1 * ZDIM + k0 + sg * 8;
  const bf16* pB0 = Bt + (size_t)(nt * 128 + rA0) * ZDIM + k0 + sg * 8;
  const bf16* pB1 = Bt + (size_t)(nt * 128 + rA1) * ZDIM + k0 + sg * 8;
  bf16* lA0 = &As[(2 * w) * 512];
  bf16* lA1 = &As[(2 * w + 1) * 512];
  bf16* lB0 = &Bs[(2 * w) * 512];
  bf16* lB1 = &Bs[(2 * w + 1) * 512];

  // fragment LDS offsets (read side swizzle)
  const int swr = (r >> 2) & 3;
  const int aoff = r * 32 + (q ^ swr) * 8;          // + mb*512
  const int boff0 = (32 * w + r) * 32 + (q ^ swr) * 8;
  const int boff1 = boff0 + 512;

  f32x4 zero4 = {0.f, 0.f, 0.f, 0.f};
  f32x4 acc[8][2];
#pragma unroll
  for (int mb = 0; mb < 8; ++mb) { acc[mb][0] = zero4; acc[mb][1] = zero4; }

  for (int s = 0; s < nsteps; ++s) {
    gl_lds16(pA0, lA0); gl_lds16(pA1, lA1);
    gl_lds16(pB0, lB0); gl_lds16(pB1, lB1);
    pA0 += 32; pA1 += 32; pB0 += 32; pB1 += 32;
    __syncthreads();
    bf16x8 bfr0 = *(const bf16x8*)&Bs[boff0];
    bf16x8 bfr1 = *(const bf16x8*)&Bs[boff1];
#pragma unroll
    for (int mb = 0; mb < 8; ++mb) {
      bf16x8 afr = *(const bf16x8*)&As[mb * 512 + aoff];
      acc[mb][0] = __builtin_amdgcn_mfma_f32_16x16x32_bf16(afr, bfr0, acc[mb][0], 0, 0, 0);
      acc[mb][1] = __builtin_amdgcn_mfma_f32_16x16x32_bf16(afr, bfr1, acc[mb][1], 0, 0, 0);
    }
    __syncthreads();
  }

  float* Pk = P + (size_t)kc * (BSZ * HIDN);
#pragma unroll
  for (int i = 0; i < 2; ++i) {
    int n = nt * 128 + (2 * w + i) * 16 + r;
#pragma unroll
    for (int mb = 0; mb < 8; ++mb) {
#pragma unroll
      for (int reg = 0; reg < 4; ++reg) {
        int brow = mb * 16 + q * 4 + reg;
        Pk[(size_t)brow * HIDN + n] = acc[mb][i][reg];
      }
    }
  }
}

// ---------- reduce partials + b1 + emb-correction + tanh -> Hb (bf16) ----------
__global__ void k_epi1(const float* __restrict__ P, const float* __restrict__ b1,
                       const float* __restrict__ W1, const float* __restrict__ E,
                       int step, bf16* __restrict__ Hb) {
  int idx = blockIdx.x * 256 + threadIdx.x;  // 128*4096
  int b = idx >> 12, n = idx & 4095;
  float s = b1[n];
#pragma unroll
  for (int c = 0; c < 8; ++c) s += P[((size_t)c * BSZ + b) * HIDN + n];
  const float* e0 = E + ((size_t)step * BSZ + b) * 6;
  const float* e1 = e0 + BSZ * 6;
#pragma unroll
  for (int j = 0; j < 6; ++j) {
    s += e0[j] * W1[(size_t)(ZDIM + j) * HIDN + n];
    s += e1[j] * W1[(size_t)(ZDIM + 6 + j) * HIDN + n];
  }
  Hb[idx] = (bf16)tanhf(s);
}

// ---------- GEMM2 + z update: z += Hb @ W2 + b2; Zb = bf16(z) ----------
// A: Hb 128 x 4096. Bt: W2t 17728 x 4096 (= W2^T). N-tile 64, 277 blocks.
__global__ __launch_bounds__(256, 2) void k_gemm2(const bf16* __restrict__ A,
                                                  const bf16* __restrict__ Bt,
                                                  const float* __restrict__ b2,
                                                  float* __restrict__ z,
                                                  bf16* __restrict__ zb) {
  __shared__ __align__(16) bf16 As[128 * 32];
  __shared__ __align__(16) bf16 Bs[64 * 32];
  const int tid = threadIdx.x;
  const int w = tid >> 6, lane = tid & 63;
  const int q = lane >> 4, r = lane & 15;
  const int nt = blockIdx.x;  // 0..276

  const int srow = lane >> 2, sslot = lane & 3;
  const int sg = sslot ^ ((srow >> 2) & 3);
  const int rA0 = (2 * w) * 16 + srow;
  const int rA1 = (2 * w + 1) * 16 + srow;
  const int rB = w * 16 + srow;  // 64 B-rows, 1 instr per wave
  const bf16* pA0 = A + (size_t)rA0 * HIDN + sg * 8;
  const bf16* pA1 = A + (size_t)rA1 * HIDN + sg * 8;
  const bf16* pB = Bt + (size_t)(nt * 64 + rB) * HIDN + sg * 8;
  bf16* lA0 = &As[(2 * w) * 512];
  bf16* lA1 = &As[(2 * w + 1) * 512];
  bf16* lB = &Bs[w * 512];

  const int swr = (r >> 2) & 3;
  const int aoff = r * 32 + (q ^ swr) * 8;
  const int boff = (w * 16 + r) * 32 + (q ^ swr) * 8;

  f32x4 zero4 = {0.f, 0.f, 0.f, 0.f};
  f32x4 acc[8];
#pragma unroll
  for (int mb = 0; mb < 8; ++mb) acc[mb] = zero4;

  for (int s = 0; s < 128; ++s) {  // K = 4096
    gl_lds16(pA0, lA0); gl_lds16(pA1, lA1); gl_lds16(pB, lB);
    pA0 += 32; pA1 += 32; pB += 32;
    __syncthreads();
    bf16x8 bfr = *(const bf16x8*)&Bs[boff];
#pragma unroll
    for (int mb = 0; mb < 8; ++mb) {
      bf16x8 afr = *(const bf16x8*)&As[mb * 512 + aoff];
      acc[mb] = __builtin_amdgcn_mfma_f32_16x16x32_bf16(afr, bfr, acc[mb], 0, 0, 0);
    }
    __syncthreads();
  }

  int n = nt * 64 + w * 16 + r;
  float bias = b2[n];
#pragma unroll
  for (int mb = 0; mb < 8; ++mb) {
#pragma unroll
    for (int reg = 0; reg < 4; ++reg) {
      int brow = mb * 16 + q * 4 + reg;
      size_t idx = (size_t)brow * ZDIM + n;
      float v = z[idx] + acc[mb][reg] + bias;
      z[idx] = v;
      zb[idx] = (bf16)v;
    }
  }
}

extern "C" void kernel_launch(void* const* d_in, const int* in_sizes, int n_in,
                              void* d_out, int out_size, void* d_ws, size_t ws_size,
                              hipStream_t stream) {
  const float* input_freq = (const float*)d_in[0];
  const int* seq = (const int*)d_in[1];
  const int* uid = (const int*)d_in[2];
  const float* cur = (const float*)d_in[3];
  const float* tar = (const float*)d_in[4];
  const float* fuse = (const float*)d_in[5];
  const float* W1 = (const float*)d_in[6];
  const float* b1 = (const float*)d_in[7];
  const float* W2 = (const float*)d_in[8];
  const float* b2 = (const float*)d_in[9];
  const int* n_poi = (const int*)d_in[10];
  float* z = (float*)d_out;

  char* ws = (char*)d_ws;
  bf16* W1t = (bf16*)ws;                              // 4096 x 17728 bf16 = 145,227,776 B
  bf16* W2t = (bf16*)(ws + 145227776);                // 17728 x 4096 bf16 = 145,227,776 B
  bf16* Zb = (bf16*)(ws + 290455552);                 // 128 x 17728 bf16  =   4,538,368 B
  bf16* Hb = (bf16*)(ws + 294993920);                 // 128 x 4096 bf16   =   1,048,576 B
  float* P = (float*)(ws + 296042496);                // 8 x 128 x 4096 f32 = 16,777,216 B
  float* E = (float*)(ws + 312819712);                // 12 x 128 x 6 f32

  // one-time per call: cast+transpose weights to bf16 (ws is re-poisoned each call)
  k_cast_transpose<<<dim3(HIDN / 32, ZDIM / 32), dim3(32, 8), 0, stream>>>(W1, W1t, ZDIM, HIDN);
  k_cast_transpose<<<dim3(ZDIM / 32, HIDN / 32), dim3(32, 8), 0, stream>>>(W2, W2t, HIDN, ZDIM);
  k_build_z0<<<dim3(70, BSZ), 256, 0, stream>>>(input_freq, seq, uid, fuse, n_poi, z, Zb);
  k_build_emb<<<1, BSZ, 0, stream>>>(cur, tar, E);

  for (int s = 0; s < 11; ++s) {
    k_gemm1<<<dim3(32, 8), 256, 0, stream>>>(Zb, W1t, P);
    k_epi1<<<2048, 256, 0, stream>>>(P, b1, W1, E, s, Hb);
    k_gemm2<<<277, 256, 0, stream>>>(Hb, W2t, b2, z, Zb);
  }
}

// Round 2
// 2140.670 us; speedup vs baseline: 1.1899x; 1.1899x over previous
//
#include <hip/hip_runtime.h>
#include <math.h>

typedef __bf16 bf16;
typedef __bf16 bf16x8 __attribute__((ext_vector_type(8)));
typedef float f32x4 __attribute__((ext_vector_type(4)));

#define ZDIM 17728
#define HIDN 4096
#define BSZ 128
#define KC1 24   // K-split chunks for GEMM1 (554 k-steps of 32)
#define KC2 4    // K-split chunks for GEMM2 (128 k-steps of 32)

__device__ __forceinline__ void gl_lds16(const bf16* g, bf16* l) {
  __builtin_amdgcn_global_load_lds(
      (const __attribute__((address_space(1))) unsigned int*)g,
      (__attribute__((address_space(3))) unsigned int*)l, 16, 0, 0);
}

// ---------- cast + transpose: src (K x N) f32 -> dst (N x K) bf16 ----------
// Tile: 64 K-rows x 32 N-cols. Writes packed bf16 pairs (4B) -> 128B per row seg.
__global__ void k_cast_transpose(const float* __restrict__ src, bf16* __restrict__ dst,
                                 int K, int N) {
  __shared__ float t[64][33];
  int tx = threadIdx.x, ty = threadIdx.y;  // 32 x 8
  int n0 = blockIdx.x * 32, k0 = blockIdx.y * 64;
#pragma unroll
  for (int i = 0; i < 64; i += 8)
    t[ty + i][tx] = src[(size_t)(k0 + ty + i) * N + (n0 + tx)];
  __syncthreads();
#pragma unroll
  for (int i = 0; i < 32; i += 8) {
    int nl = ty + i;
    union { bf16 h[2]; unsigned u; } p;
    p.h[0] = (bf16)t[2 * tx][nl];
    p.h[1] = (bf16)t[2 * tx + 1][nl];
    *(unsigned*)&dst[(size_t)(n0 + nl) * K + k0 + 2 * tx] = p.u;
  }
}

// ---------- build z0 (fp32 into d_out, bf16 copy) ----------
__global__ void k_build_z0(const float* __restrict__ input_freq, const int* __restrict__ seq,
                           const int* __restrict__ uid, const float* __restrict__ fuse,
                           const int* __restrict__ n_poi_p,
                           float* __restrict__ z, bf16* __restrict__ zb) {
  int n = blockIdx.x * 256 + threadIdx.x;
  int b = blockIdx.y;
  if (n >= ZDIM) return;
  float v;
  if (n < 9408) {
    v = input_freq[b * 3136 + (n % 3136)];
  } else if (n < 17600) {
    int m = n - 9408;
    int d = m >> 6, l = m & 63;
    v = fuse[(size_t)seq[b * 64 + l] * 128 + d];
  } else {
    int d = n - 17600;
    v = fuse[(size_t)(n_poi_p[0] + uid[b]) * 128 + d];
  }
  size_t idx = (size_t)b * ZDIM + n;
  z[idx] = v;
  zb[idx] = (bf16)v;
}

// ---------- time grid + sin/cos embedding: E[12][128][6] ----------
__global__ void k_build_emb(const float* __restrict__ cur, const float* __restrict__ tar,
                            float* __restrict__ E) {
  int b = threadIdx.x;  // 128 threads
  const float P[3] = {24.0f, 7.0f, 365.0f};
  const float TWO_PI = 6.283185307179586f;
  float t[3];
  for (int c = 0; c < 3; ++c) t[c] = cur[b * 3 + c];
  int r = 0;
  for (int j = 0; j < 3; ++j) {
    float s = cur[b * 3 + j], e = tar[b * 3 + j];
    bool wrap = s > e;
    float ea = wrap ? (e + P[j]) : e;
    for (int k = 0; k < 4; ++k) {
      float frac = (float)k / 3.0f;
      float v = s + (ea - s) * frac;
      if (wrap) v = v - floorf(v / P[j]) * P[j];
      t[j] = v;
      for (int c = 0; c < 3; ++c) {
        float ph = TWO_PI * t[c] / P[c];
        E[(r * BSZ + b) * 6 + c] = sinf(ph);
        E[(r * BSZ + b) * 6 + 3 + c] = cosf(ph);
      }
      ++r;
    }
  }
}

// ---------- GEMM1 partial: P[kc] = A(128 x Kchunk) * W1t^T ----------
// A: Zb 128 x 17728 row-major (bf16). Bt: W1t 4096 x 17728 row-major (= W1^T).
// 554 k-steps split into KC1 chunks: first 2 chunks get 24, rest 23.
__global__ __launch_bounds__(256, 3) void k_gemm1(const bf16* __restrict__ A,
                                                  const bf16* __restrict__ Bt,
                                                  float* __restrict__ P) {
  __shared__ __align__(16) bf16 As[128 * 32];
  __shared__ __align__(16) bf16 Bs[128 * 32];
  const int tid = threadIdx.x;
  const int w = tid >> 6, lane = tid & 63;
  const int q = lane >> 4, r = lane & 15;
  const int nt = blockIdx.x, kc = blockIdx.y;
  const int nsteps = 23 + (kc < 2 ? 1 : 0);
  const int kstart = kc * 23 + (kc < 2 ? kc : 2);

  const int srow = lane >> 2, sslot = lane & 3;
  const int sg = sslot ^ ((srow >> 2) & 3);
  const int rA0 = (2 * w) * 16 + srow;
  const int rA1 = (2 * w + 1) * 16 + srow;
  long k0 = (long)kstart * 32;
  const bf16* pA0 = A + (size_t)rA0 * ZDIM + k0 + sg * 8;
  const bf16* pA1 = A + (size_t)rA1 * ZDIM + k0 + sg * 8;
  const bf16* pB0 = Bt + (size_t)(nt * 128 + rA0) * ZDIM + k0 + sg * 8;
  const bf16* pB1 = Bt + (size_t)(nt * 128 + rA1) * ZDIM + k0 + sg * 8;
  bf16* lA0 = &As[(2 * w) * 512];
  bf16* lA1 = &As[(2 * w + 1) * 512];
  bf16* lB0 = &Bs[(2 * w) * 512];
  bf16* lB1 = &Bs[(2 * w + 1) * 512];

  const int swr = (r >> 2) & 3;
  const int aoff = r * 32 + (q ^ swr) * 8;
  const int boff0 = (32 * w + r) * 32 + (q ^ swr) * 8;
  const int boff1 = boff0 + 512;

  f32x4 zero4 = {0.f, 0.f, 0.f, 0.f};
  f32x4 acc[8][2];
#pragma unroll
  for (int mb = 0; mb < 8; ++mb) { acc[mb][0] = zero4; acc[mb][1] = zero4; }

  for (int s = 0; s < nsteps; ++s) {
    gl_lds16(pA0, lA0); gl_lds16(pA1, lA1);
    gl_lds16(pB0, lB0); gl_lds16(pB1, lB1);
    pA0 += 32; pA1 += 32; pB0 += 32; pB1 += 32;
    __syncthreads();
    bf16x8 bfr0 = *(const bf16x8*)&Bs[boff0];
    bf16x8 bfr1 = *(const bf16x8*)&Bs[boff1];
#pragma unroll
    for (int mb = 0; mb < 8; ++mb) {
      bf16x8 afr = *(const bf16x8*)&As[mb * 512 + aoff];
      acc[mb][0] = __builtin_amdgcn_mfma_f32_16x16x32_bf16(afr, bfr0, acc[mb][0], 0, 0, 0);
      acc[mb][1] = __builtin_amdgcn_mfma_f32_16x16x32_bf16(afr, bfr1, acc[mb][1], 0, 0, 0);
    }
    __syncthreads();
  }

  float* Pk = P + (size_t)kc * (BSZ * HIDN);
#pragma unroll
  for (int i = 0; i < 2; ++i) {
    int n = nt * 128 + (2 * w + i) * 16 + r;
#pragma unroll
    for (int mb = 0; mb < 8; ++mb) {
#pragma unroll
      for (int reg = 0; reg < 4; ++reg) {
        int brow = mb * 16 + q * 4 + reg;
        Pk[(size_t)brow * HIDN + n] = acc[mb][i][reg];
      }
    }
  }
}

// ---------- reduce partials + b1 + emb-correction + tanh -> Hb (bf16) ----------
__global__ void k_epi1(const float* __restrict__ P, const float* __restrict__ b1,
                       const float* __restrict__ W1, const float* __restrict__ E,
                       int step, bf16* __restrict__ Hb) {
  int idx = blockIdx.x * 256 + threadIdx.x;  // 128*4096
  int b = idx >> 12, n = idx & 4095;
  float s = b1[n];
#pragma unroll
  for (int c = 0; c < KC1; ++c) s += P[((size_t)c * BSZ + b) * HIDN + n];
  const float* e0 = E + ((size_t)step * BSZ + b) * 6;
  const float* e1 = e0 + BSZ * 6;
#pragma unroll
  for (int j = 0; j < 6; ++j) {
    s += e0[j] * W1[(size_t)(ZDIM + j) * HIDN + n];
    s += e1[j] * W1[(size_t)(ZDIM + 6 + j) * HIDN + n];
  }
  Hb[idx] = (bf16)tanhf(s);
}

// ---------- GEMM2 partial: P2[kc] = Hb(128 x Kchunk) * W2t^T ----------
// A: Hb 128 x 4096. Bt: W2t 17728 x 4096 (= W2^T). N-tile 64, K split KC2 ways.
__global__ __launch_bounds__(256, 4) void k_gemm2(const bf16* __restrict__ A,
                                                  const bf16* __restrict__ Bt,
                                                  float* __restrict__ P2) {
  __shared__ __align__(16) bf16 As[128 * 32];
  __shared__ __align__(16) bf16 Bs[64 * 32];
  const int tid = threadIdx.x;
  const int w = tid >> 6, lane = tid & 63;
  const int q = lane >> 4, r = lane & 15;
  const int nt = blockIdx.x;   // 0..276
  const int kc = blockIdx.y;   // 0..KC2-1
  const long k0 = (long)kc * 32 * 32;  // 32 k-steps per chunk

  const int srow = lane >> 2, sslot = lane & 3;
  const int sg = sslot ^ ((srow >> 2) & 3);
  const int rA0 = (2 * w) * 16 + srow;
  const int rA1 = (2 * w + 1) * 16 + srow;
  const int rB = w * 16 + srow;
  const bf16* pA0 = A + (size_t)rA0 * HIDN + k0 + sg * 8;
  const bf16* pA1 = A + (size_t)rA1 * HIDN + k0 + sg * 8;
  const bf16* pB = Bt + (size_t)(nt * 64 + rB) * HIDN + k0 + sg * 8;
  bf16* lA0 = &As[(2 * w) * 512];
  bf16* lA1 = &As[(2 * w + 1) * 512];
  bf16* lB = &Bs[w * 512];

  const int swr = (r >> 2) & 3;
  const int aoff = r * 32 + (q ^ swr) * 8;
  const int boff = (w * 16 + r) * 32 + (q ^ swr) * 8;

  f32x4 zero4 = {0.f, 0.f, 0.f, 0.f};
  f32x4 acc[8];
#pragma unroll
  for (int mb = 0; mb < 8; ++mb) acc[mb] = zero4;

  for (int s = 0; s < 32; ++s) {
    gl_lds16(pA0, lA0); gl_lds16(pA1, lA1); gl_lds16(pB, lB);
    pA0 += 32; pA1 += 32; pB += 32;
    __syncthreads();
    bf16x8 bfr = *(const bf16x8*)&Bs[boff];
#pragma unroll
    for (int mb = 0; mb < 8; ++mb) {
      bf16x8 afr = *(const bf16x8*)&As[mb * 512 + aoff];
      acc[mb] = __builtin_amdgcn_mfma_f32_16x16x32_bf16(afr, bfr, acc[mb], 0, 0, 0);
    }
    __syncthreads();
  }

  float* Pk = P2 + (size_t)kc * (BSZ * ZDIM);
  int n = nt * 64 + w * 16 + r;
#pragma unroll
  for (int mb = 0; mb < 8; ++mb) {
#pragma unroll
    for (int reg = 0; reg < 4; ++reg) {
      int brow = mb * 16 + q * 4 + reg;
      Pk[(size_t)brow * ZDIM + n] = acc[mb][reg];
    }
  }
}

// ---------- reduce GEMM2 partials + b2, update z, write zb ----------
__global__ void k_epi2(const float* __restrict__ P2, const float* __restrict__ b2,
                       float* __restrict__ z, bf16* __restrict__ zb) {
  int idx = blockIdx.x * 256 + threadIdx.x;  // 128*17728 = 2,269,184
  int n = idx % ZDIM;
  float s = b2[n];
#pragma unroll
  for (int c = 0; c < KC2; ++c) s += P2[(size_t)c * (BSZ * ZDIM) + idx];
  float v = z[idx] + s;
  z[idx] = v;
  zb[idx] = (bf16)v;
}

extern "C" void kernel_launch(void* const* d_in, const int* in_sizes, int n_in,
                              void* d_out, int out_size, void* d_ws, size_t ws_size,
                              hipStream_t stream) {
  const float* input_freq = (const float*)d_in[0];
  const int* seq = (const int*)d_in[1];
  const int* uid = (const int*)d_in[2];
  const float* cur = (const float*)d_in[3];
  const float* tar = (const float*)d_in[4];
  const float* fuse = (const float*)d_in[5];
  const float* W1 = (const float*)d_in[6];
  const float* b1 = (const float*)d_in[7];
  const float* W2 = (const float*)d_in[8];
  const float* b2 = (const float*)d_in[9];
  const int* n_poi = (const int*)d_in[10];
  float* z = (float*)d_out;

  char* ws = (char*)d_ws;
  bf16* W1t = (bf16*)ws;                              // 4096 x 17728 bf16 = 145,227,776 B
  bf16* W2t = (bf16*)(ws + 145227776);                // 17728 x 4096 bf16 = 145,227,776 B
  bf16* Zb = (bf16*)(ws + 290455552);                 // 128 x 17728 bf16
  bf16* Hb = (bf16*)(ws + 294993920);                 // 128 x 4096 bf16
  float* P = (float*)(ws + 296042496);                // KC1 x 128 x 4096 f32 = 50,331,648 B
  float* P2 = (float*)(ws + 296042496 + 50331648);    // KC2 x 128 x 17728 f32 = 36,306,944 B
  float* E = (float*)(ws + 296042496 + 50331648 + 36306944);  // 12 x 128 x 6 f32

  k_cast_transpose<<<dim3(HIDN / 32, ZDIM / 64), dim3(32, 8), 0, stream>>>(W1, W1t, ZDIM, HIDN);
  k_cast_transpose<<<dim3(ZDIM / 32, HIDN / 64), dim3(32, 8), 0, stream>>>(W2, W2t, HIDN, ZDIM);
  k_build_z0<<<dim3(70, BSZ), 256, 0, stream>>>(input_freq, seq, uid, fuse, n_poi, z, Zb);
  k_build_emb<<<1, BSZ, 0, stream>>>(cur, tar, E);

  for (int s = 0; s < 11; ++s) {
    k_gemm1<<<dim3(32, KC1), 256, 0, stream>>>(Zb, W1t, P);
    k_epi1<<<2048, 256, 0, stream>>>(P, b1, W1, E, s, Hb);
    k_gemm2<<<dim3(277, KC2), 256, 0, stream>>>(Hb, W2t, P2);
    k_epi2<<<8864, 256, 0, stream>>>(P2, b2, z, Zb);
  }
}